// Round 8
// baseline (379.668 us; speedup 1.0000x reference)
//
#include <hip/hip_runtime.h>
#include <stdint.h>

typedef __attribute__((ext_vector_type(8))) short bf16x8;
typedef __attribute__((ext_vector_type(4))) float f32x4;

#define D_IN  4096
#define D_OUT 4096
#define KC 512   // per-component input dim
#define NC 512   // per-component output dim
#define NT 64    // K-tiles of BK=64

// SIGN_TABLE[i][j], row-major
__constant__ float c_sign[64] = {
 +1,-1,-1,-1,-1,-1,-1,-1,
 +1,+1,+1,-1,+1,-1,-1,+1,
 +1,-1,+1,+1,+1,+1,-1,-1,
 +1,+1,-1,+1,+1,-1,+1,-1,
 +1,-1,-1,-1,+1,+1,+1,+1,
 +1,+1,-1,+1,-1,+1,-1,+1,
 +1,+1,+1,-1,-1,+1,+1,-1,
 +1,-1,+1,+1,-1,-1,+1,+1,
};

__device__ inline unsigned int pack2bf16(float a, float b) {
    unsigned int ua = __builtin_bit_cast(unsigned int, a);
    unsigned int ub = __builtin_bit_cast(unsigned int, b);
    ua = (ua + 0x7FFFu + ((ua >> 16) & 1u)) >> 16;
    ub = (ub + 0x7FFFu + ((ub >> 16) & 1u)) >> 16;
    return ua | (ub << 16);
}

typedef __attribute__((address_space(1))) const unsigned int gas_u32;
typedef __attribute__((address_space(3))) unsigned int las_u32;
#define ASYNC16(g, l) __builtin_amdgcn_global_load_lds((gas_u32*)(g), (las_u32*)(l), 16, 0, 0)
#define SBAR0() __builtin_amdgcn_sched_barrier(0)
#define ENDP do { __builtin_amdgcn_s_barrier(); asm volatile("" ::: "memory"); } while (0)

// ---------- pre-conversion kernels ----------

__global__ __launch_bounds__(256)
void conv_x(const float* __restrict__ in, unsigned short* __restrict__ out, int n8) {
    int i = blockIdx.x * blockDim.x + threadIdx.x;
    if (i >= n8) return;
    const float4 a = ((const float4*)in)[(size_t)i * 2];
    const float4 b = ((const float4*)in)[(size_t)i * 2 + 1];
    uint4 o;
    o.x = pack2bf16(a.x, a.y); o.y = pack2bf16(a.z, a.w);
    o.z = pack2bf16(b.x, b.y); o.w = pack2bf16(b.z, b.w);
    ((uint4*)out)[i] = o;
}

// Wbig[i*512+n][j*512+k] = sign[i][j] * W[i^j][n][k], fp32 -> bf16
__global__ __launch_bounds__(256)
void conv_w(const float* __restrict__ W, unsigned short* __restrict__ out) {
    int gid = blockIdx.x * blockDim.x + threadIdx.x;   // 0 .. 4096*512-1
    int row = gid >> 9;
    int c8  = gid & 511;
    int i = row >> 9, n = row & 511;
    int j = c8 >> 6;
    int k = (c8 & 63) << 3;
    float sgn = c_sign[i * 8 + j];
    const float* src = W + ((((i ^ j) * NC + n) * KC) + k);
    float4 a = *(const float4*)(src);
    float4 b = *(const float4*)(src + 4);
    uint4 o;
    o.x = pack2bf16(a.x * sgn, a.y * sgn); o.y = pack2bf16(a.z * sgn, a.w * sgn);
    o.z = pack2bf16(b.x * sgn, b.y * sgn); o.w = pack2bf16(b.z * sgn, b.w * sgn);
    ((uint4*)out)[gid] = o;
}

// ---------- 256x256 bf16 GEMM: A via LDS, B direct global->VGPR ----------

__device__ __forceinline__ void read_a(bf16x8 (&d)[4], const unsigned short* buf,
                                       int mh, int kk, int lane, int wr) {
#pragma unroll
    for (int f = 0; f < 4; ++f) {
        const int r  = wr * 128 + (mh * 4 + f) * 16 + (lane & 15);
        const int ch = (kk * 4 + (lane >> 4)) ^ (r & 7);
        d[f] = *(const bf16x8*)((const char*)buf + r * 128 + (ch << 4));
    }
}

// B fragment straight from global: row = wc*64 + n*16 + (lane&15),
// k = kk*32 + (lane>>4)*8 .. +7 — identical (row,k) mapping as the old LDS
// read, minus the swizzle (which was an LDS artifact). Lanes with the same
// row read contiguous 64B -> 16 x 64B requests per instruction.
__device__ __forceinline__ bf16x8 gload_b(const unsigned short* gB, int n, int kk,
                                          int lane, int wc) {
    const size_t off = (size_t)(wc * 64 + n * 16 + (lane & 15)) * D_IN
                     + kk * 32 + (lane >> 4) * 8;
    return *(const bf16x8*)(gB + off);
}

__device__ __forceinline__ void mfma16(f32x4 (&acc)[8][4], int mh,
                                       const bf16x8 (&a)[4], const bf16x8 (&b)[4]) {
#pragma unroll
    for (int f = 0; f < 4; ++f)
#pragma unroll
        for (int n = 0; n < 4; ++n)
            acc[mh * 4 + f][n] = __builtin_amdgcn_mfma_f32_16x16x32_bf16(
                a[f], b[n], acc[mh * 4 + f][n], 0, 0, 0);
}

// One K-tile (BK=64), 4 windows (mh,kh). A-frags from LDS (read in-window,
// compiler lgkm before MFMA => every ds_read provably completes before the
// window's 2nd barrier). B for the NEXT tile loaded to regs (2 frags/window).
// A(u+1) staged at P0/P1; vmcnt(6) at P3 end (SBAR0-pinned issue order:
// [Ah0,Ah0,b,b, Ah1,Ah1,b,b, b,b, b,b] -> 6 newest are all B-reg loads,
// so all 4 ASYNC16 are drained) guarantees A(u+1) is in LDS before the
// next tile's read_a. B-reg uses are compiler-vmcnt-tracked.
__device__ __forceinline__ void tile_bg(
    const unsigned short* Acur, unsigned short* Aoth,
    const unsigned short* gA1, const unsigned short* gB1,
    f32x4 (&acc)[8][4],
    bf16x8 (&bc0)[4], bf16x8 (&bc1)[4],
    bf16x8 (&bn0)[4], bf16x8 (&bn1)[4],
    size_t goff0, size_t goff1, int loff0, int loff1,
    int lane, int wr, int wc)
{
    bf16x8 a[4];
    // ---- P0: (mh0,kh0) ----
    read_a(a, Acur, 0, 0, lane, wr);
    ASYNC16(gA1 + goff0, Aoth + loff0);
    ASYNC16(gA1 + goff1, Aoth + loff1);
    SBAR0();
    bn0[0] = gload_b(gB1, 0, 0, lane, wc);
    bn0[1] = gload_b(gB1, 1, 0, lane, wc);
    SBAR0();
    __builtin_amdgcn_s_barrier();
    SBAR0();
    __builtin_amdgcn_s_setprio(1);
    mfma16(acc, 0, a, bc0);
    __builtin_amdgcn_s_setprio(0);
    SBAR0();
    ENDP;
    // ---- P1: (mh1,kh0) ----
    read_a(a, Acur, 1, 0, lane, wr);
    ASYNC16(gA1 + 128 * D_IN + goff0, Aoth + 8192 + loff0);
    ASYNC16(gA1 + 128 * D_IN + goff1, Aoth + 8192 + loff1);
    SBAR0();
    bn0[2] = gload_b(gB1, 2, 0, lane, wc);
    bn0[3] = gload_b(gB1, 3, 0, lane, wc);
    SBAR0();
    __builtin_amdgcn_s_barrier();
    SBAR0();
    __builtin_amdgcn_s_setprio(1);
    mfma16(acc, 1, a, bc0);
    __builtin_amdgcn_s_setprio(0);
    SBAR0();
    ENDP;
    // ---- P2: (mh0,kh1) ----
    read_a(a, Acur, 0, 1, lane, wr);
    bn1[0] = gload_b(gB1, 0, 1, lane, wc);
    bn1[1] = gload_b(gB1, 1, 1, lane, wc);
    SBAR0();
    __builtin_amdgcn_s_barrier();
    SBAR0();
    __builtin_amdgcn_s_setprio(1);
    mfma16(acc, 0, a, bc1);
    __builtin_amdgcn_s_setprio(0);
    SBAR0();
    ENDP;
    // ---- P3: (mh1,kh1) ----
    read_a(a, Acur, 1, 1, lane, wr);
    bn1[2] = gload_b(gB1, 2, 1, lane, wc);
    bn1[3] = gload_b(gB1, 3, 1, lane, wc);
    SBAR0();
    __builtin_amdgcn_s_barrier();
    SBAR0();
    __builtin_amdgcn_s_setprio(1);
    mfma16(acc, 1, a, bc1);
    __builtin_amdgcn_s_setprio(0);
    SBAR0();
    asm volatile("s_waitcnt vmcnt(6)");   // drains all 4 A-stage DMAs (see above)
    ENDP;
}

__global__ __launch_bounds__(512, 2)
void octo_gemm_8ph(const unsigned short* __restrict__ Xb,
                   const unsigned short* __restrict__ Wb,
                   float* __restrict__ Y, int M)
{
    // LDS: A only, 2 K-tile double buffer, 256x64 bf16 each = 64 KiB total.
    // Element (r,k): byte r*128 + ((chunk ^ (r&7))<<4) + low, chunk=(k*2)>>4;
    // linear LDS dest + inverse-swizzled GLOBAL source (rule #21).
    __shared__ __align__(16) unsigned short sm[32768];
    unsigned short* A0 = sm;
    unsigned short* A1 = sm + 16384;

    const int tid  = threadIdx.x;
    const int lane = tid & 63;
    const int wave = tid >> 6;
    const int wr   = wave >> 2;      // 2x4 wave grid; wave owns 128x64 output
    const int wc   = wave & 3;

    const int nbn = D_OUT / 256;                // 16
    const int nwg = (M / 256) * nbn;            // 512
    int bid = blockIdx.x;
    int cpx = nwg >> 3;                         // bijective XCD swizzle (nwg%8==0)
    int wg  = (bid & 7) * cpx + (bid >> 3);
    const int bm = wg / nbn, bn = wg % nbn;
    const int row0 = bm * 256, col0 = bn * 256;

    // A staging geometry: half-tile = 128 rows x 64 cols bf16; 2 loads/thread
    const int srow  = tid >> 3;                 // 0..63
    const int sch   = tid & 7;                  // 16B chunk
    const size_t goff0 = (size_t)srow * D_IN + (size_t)((sch ^ (srow & 7)) * 8);
    const size_t goff1 = goff0 + (size_t)64 * D_IN;   // (64+srow)&7 == srow&7
    const int loff0 = tid * 8;                  // ushort elems; = lane*16B per wave
    const int loff1 = loff0 + 4096;

    const unsigned short* gX = Xb + (size_t)row0 * D_IN;
    const unsigned short* gW = Wb + (size_t)col0 * D_IN;

    f32x4 acc[8][4];
    #pragma unroll
    for (int m = 0; m < 8; ++m)
        #pragma unroll
        for (int n = 0; n < 4; ++n)
            acc[m][n] = (f32x4){0.f, 0.f, 0.f, 0.f};

    // ---- prologue: A(0) -> A0 (4 DMAs), B(0) frags -> regs (8 loads) ----
    ASYNC16(gX + goff0, A0 + loff0);
    ASYNC16(gX + goff1, A0 + loff1);
    ASYNC16(gX + 128 * D_IN + goff0, A0 + 8192 + loff0);
    ASYNC16(gX + 128 * D_IN + goff1, A0 + 8192 + loff1);
    SBAR0();
    bf16x8 bA0[4], bA1[4], bB0[4], bB1[4];
    bA0[0] = gload_b(gW, 0, 0, lane, wc);
    bA0[1] = gload_b(gW, 1, 0, lane, wc);
    bA0[2] = gload_b(gW, 2, 0, lane, wc);
    bA0[3] = gload_b(gW, 3, 0, lane, wc);
    bA1[0] = gload_b(gW, 0, 1, lane, wc);
    bA1[1] = gload_b(gW, 1, 1, lane, wc);
    bA1[2] = gload_b(gW, 2, 1, lane, wc);
    bA1[3] = gload_b(gW, 3, 1, lane, wc);
    SBAR0();
    asm volatile("s_waitcnt vmcnt(8)");   // A(0) landed; B regs compiler-tracked
    ENDP;

    for (int i = 0; i < NT / 2; ++i) {
        const int u = 2 * i;
        // tail iterations load wrapped tiles (&63): uniform vmcnt counts;
        // wrapped data lands in regions/regs never used again (race-free).
        const unsigned short* gA1t = gX + ((u + 1) & (NT - 1)) * 64;
        const unsigned short* gB1t = gW + ((u + 1) & (NT - 1)) * 64;
        const unsigned short* gA2t = gX + ((u + 2) & (NT - 1)) * 64;
        const unsigned short* gB2t = gW + ((u + 2) & (NT - 1)) * 64;

        // tile u: A from A0, B from bA*; stage A(u+1)->A1, load B(u+1)->bB*
        tile_bg(A0, A1, gA1t, gB1t, acc, bA0, bA1, bB0, bB1,
                goff0, goff1, loff0, loff1, lane, wr, wc);
        // tile u+1: A from A1, B from bB*; stage A(u+2)->A0, load B(u+2)->bA*
        tile_bg(A1, A0, gA2t, gB2t, acc, bB0, bB1, bA0, bA1,
                goff0, goff1, loff0, loff1, lane, wr, wc);
    }

    // epilogue: C/D layout col=lane&15, row=(lane>>4)*4+reg  [m89/m91]
    const int rl = (lane >> 4) << 2;
    const int cl = lane & 15;
    #pragma unroll
    for (int m = 0; m < 8; ++m) {
        const int rg = row0 + wr * 128 + m * 16 + rl;
        #pragma unroll
        for (int n = 0; n < 4; ++n) {
            const int cg = col0 + wc * 64 + n * 16 + cl;
            #pragma unroll
            for (int q = 0; q < 4; ++q)
                Y[(size_t)(rg + q) * D_OUT + cg] = acc[m][n][q];
        }
    }
}

// ---------- fallback: fused fp32-staging kernel (no workspace) ----------

#define BM 128
#define BN 128
#define BK 64

__global__ __launch_bounds__(256)
void octo_gemm_f32(const float* __restrict__ X, const float* __restrict__ W,
                   float* __restrict__ Y, int M)
{
    __shared__ __align__(16) unsigned short As[BM * BK];
    __shared__ __align__(16) unsigned short Bs[BN * BK];

    const int tid  = threadIdx.x;
    const int lane = tid & 63;
    const int wave = tid >> 6;
    const int wr   = wave >> 1;
    const int wc   = wave & 1;

    const int nbn = D_OUT / BN;
    const int nwg = (M / BM) * nbn;
    int bid = blockIdx.x;
    int wg  = bid;
    if ((nwg & 7) == 0) {
        int cpx = nwg >> 3;
        wg = (bid & 7) * cpx + (bid >> 3);
    }
    const int bm = wg / nbn, bn = wg % nbn;
    const int row0  = bm * BM;
    const int col0  = bn * BN;
    const int icomp = col0 >> 9;
    const int noff  = col0 & (NC - 1);

    const int srow = tid >> 4;
    const int scol = (tid & 15) << 2;

    f32x4 acc[4][4];
    #pragma unroll
    for (int m = 0; m < 4; ++m)
        #pragma unroll
        for (int n = 0; n < 4; ++n)
            acc[m][n] = (f32x4){0.f, 0.f, 0.f, 0.f};

    char* AsB = (char*)As;
    char* BsB = (char*)Bs;
    const int byteC = scol << 1;

    for (int step = 0; step < NT; ++step) {
        const int k0 = step * BK;
        const int j  = k0 >> 9;
        const int kc = k0 & (KC - 1);
        const float sgn = c_sign[icomp * 8 + j];
        const int   w   = icomp ^ j;
        const float* Wp = W + (((size_t)w * NC + noff) * KC + kc);
        const float* Xp = X + ((size_t)row0 * D_IN + k0);

        __syncthreads();
        #pragma unroll
        for (int p = 0; p < 8; ++p) {
            const int r  = p * 16 + srow;
            const int sb = r * 128 + ((((byteC >> 4) ^ (r & 7)) << 4)) + (byteC & 8);
            const float4 va = *(const float4*)(&Xp[(size_t)r * D_IN + scol]);
            *(uint2*)(AsB + sb) = make_uint2(pack2bf16(va.x, va.y),
                                             pack2bf16(va.z, va.w));
            const float4 vb = *(const float4*)(&Wp[(size_t)r * KC + scol]);
            *(uint2*)(BsB + sb) = make_uint2(pack2bf16(vb.x * sgn, vb.y * sgn),
                                             pack2bf16(vb.z * sgn, vb.w * sgn));
        }
        __syncthreads();

        #pragma unroll
        for (int kk = 0; kk < 2; ++kk) {
            bf16x8 af[4], bf[4];
            #pragma unroll
            for (int m = 0; m < 4; ++m) {
                const int r = wr * 64 + m * 16 + (lane & 15);
                const int chunk = (kk * 4 + (lane >> 4)) ^ (r & 7);
                af[m] = *(const bf16x8*)(AsB + r * 128 + (chunk << 4));
            }
            #pragma unroll
            for (int n = 0; n < 4; ++n) {
                const int r = wc * 64 + n * 16 + (lane & 15);
                const int chunk = (kk * 4 + (lane >> 4)) ^ (r & 7);
                bf[n] = *(const bf16x8*)(BsB + r * 128 + (chunk << 4));
            }
            #pragma unroll
            for (int m = 0; m < 4; ++m)
                #pragma unroll
                for (int n = 0; n < 4; ++n)
                    acc[m][n] = __builtin_amdgcn_mfma_f32_16x16x32_bf16(
                        af[m], bf[n], acc[m][n], 0, 0, 0);
        }
    }

    const int rl = (lane >> 4) << 2;
    const int cl = lane & 15;
    #pragma unroll
    for (int m = 0; m < 4; ++m) {
        const int rg = row0 + wr * 64 + m * 16 + rl;
        #pragma unroll
        for (int n = 0; n < 4; ++n) {
            const int cg = col0 + wc * 64 + n * 16 + cl;
            #pragma unroll
            for (int q = 0; q < 4; ++q)
                Y[(size_t)(rg + q) * D_OUT + cg] = acc[m][n][q];
        }
    }
}

extern "C" void kernel_launch(void* const* d_in, const int* in_sizes, int n_in,
                              void* d_out, int out_size, void* d_ws, size_t ws_size,
                              hipStream_t stream) {
    const float* X = (const float*)d_in[0];   // [B*T, 4096] fp32
    const float* W = (const float*)d_in[1];   // [8, 512, 512] fp32
    float* Y = (float*)d_out;                 // [B*T, 4096] fp32
    const int M = in_sizes[0] / D_IN;         // 8192

    const size_t xb_bytes = (size_t)M * D_IN * sizeof(unsigned short);      // 64 MB
    const size_t wb_bytes = (size_t)D_OUT * D_IN * sizeof(unsigned short);  // 32 MB

    if (ws_size >= xb_bytes + wb_bytes && (M % 256) == 0) {
        unsigned short* Xb = (unsigned short*)d_ws;
        unsigned short* Wb = (unsigned short*)((char*)d_ws + xb_bytes);
        const int n8x = M * D_IN / 8;
        hipLaunchKernelGGL(conv_x, dim3(n8x / 256), dim3(256), 0, stream, X, Xb, n8x);
        hipLaunchKernelGGL(conv_w, dim3((D_OUT * D_IN / 8) / 256), dim3(256), 0, stream, W, Wb);
        const int nwg = (M / 256) * (D_OUT / 256);   // 512
        hipLaunchKernelGGL(octo_gemm_8ph, dim3(nwg), dim3(512), 0, stream, Xb, Wb, Y, M);
    } else {
        const int nwg = (M / BM) * (D_OUT / BN);
        hipLaunchKernelGGL(octo_gemm_f32, dim3(nwg), dim3(256), 0, stream, X, W, Y, M);
    }
}

// Round 9
// 257.650 us; speedup vs baseline: 1.4736x; 1.4736x over previous
//
#include <hip/hip_runtime.h>
#include <stdint.h>

typedef __attribute__((ext_vector_type(8))) short bf16x8;
typedef __attribute__((ext_vector_type(4))) float f32x4;

#define D_IN  4096
#define D_OUT 4096
#define KC 512   // per-component input dim
#define NC 512   // per-component output dim
#define NT 64    // K-tiles of BK=64

// SIGN_TABLE[i][j], row-major
__constant__ float c_sign[64] = {
 +1,-1,-1,-1,-1,-1,-1,-1,
 +1,+1,+1,-1,+1,-1,-1,+1,
 +1,-1,+1,+1,+1,+1,-1,-1,
 +1,+1,-1,+1,+1,-1,+1,-1,
 +1,-1,-1,-1,+1,+1,+1,+1,
 +1,+1,-1,+1,-1,+1,-1,+1,
 +1,+1,+1,-1,-1,+1,+1,-1,
 +1,-1,+1,+1,-1,-1,+1,+1,
};

__device__ inline unsigned int pack2bf16(float a, float b) {
    unsigned int ua = __builtin_bit_cast(unsigned int, a);
    unsigned int ub = __builtin_bit_cast(unsigned int, b);
    ua = (ua + 0x7FFFu + ((ua >> 16) & 1u)) >> 16;
    ub = (ub + 0x7FFFu + ((ub >> 16) & 1u)) >> 16;
    return ua | (ub << 16);
}

typedef __attribute__((address_space(1))) const unsigned int gas_u32;
typedef __attribute__((address_space(3))) unsigned int las_u32;
#define ASYNC16(g, l) __builtin_amdgcn_global_load_lds((gas_u32*)(g), (las_u32*)(l), 16, 0, 0)
#define SBAR0() __builtin_amdgcn_sched_barrier(0)
#define ENDP do { __builtin_amdgcn_s_barrier(); asm volatile("" ::: "memory"); } while (0)

// ---------- pre-conversion kernels ----------

__global__ __launch_bounds__(256)
void conv_x(const float* __restrict__ in, unsigned short* __restrict__ out, int n8) {
    int i = blockIdx.x * blockDim.x + threadIdx.x;
    if (i >= n8) return;
    const float4 a = ((const float4*)in)[(size_t)i * 2];
    const float4 b = ((const float4*)in)[(size_t)i * 2 + 1];
    uint4 o;
    o.x = pack2bf16(a.x, a.y); o.y = pack2bf16(a.z, a.w);
    o.z = pack2bf16(b.x, b.y); o.w = pack2bf16(b.z, b.w);
    ((uint4*)out)[i] = o;
}

// Wbig[i*512+n][j*512+k] = sign[i][j] * W[i^j][n][k], fp32 -> bf16
__global__ __launch_bounds__(256)
void conv_w(const float* __restrict__ W, unsigned short* __restrict__ out) {
    int gid = blockIdx.x * blockDim.x + threadIdx.x;   // 0 .. 4096*512-1
    int row = gid >> 9;
    int c8  = gid & 511;
    int i = row >> 9, n = row & 511;
    int j = c8 >> 6;
    int k = (c8 & 63) << 3;
    float sgn = c_sign[i * 8 + j];
    const float* src = W + ((((i ^ j) * NC + n) * KC) + k);
    float4 a = *(const float4*)(src);
    float4 b = *(const float4*)(src + 4);
    uint4 o;
    o.x = pack2bf16(a.x * sgn, a.y * sgn); o.y = pack2bf16(a.z * sgn, a.w * sgn);
    o.z = pack2bf16(b.x * sgn, b.y * sgn); o.w = pack2bf16(b.z * sgn, b.w * sgn);
    ((uint4*)out)[gid] = o;
}

// ---------- 256x256 bf16 GEMM, one-ahead pipeline, 1 barrier/phase ----------

__device__ __forceinline__ void read_a(bf16x8 (&d)[4], const unsigned short* buf,
                                       int mh, int kk, int lane, int wr) {
#pragma unroll
    for (int f = 0; f < 4; ++f) {
        const int r  = wr * 128 + (mh * 4 + f) * 16 + (lane & 15);
        const int ch = (kk * 4 + (lane >> 4)) ^ (r & 7);
        d[f] = *(const bf16x8*)((const char*)buf + r * 128 + (ch << 4));
    }
}

__device__ __forceinline__ void read_b(bf16x8 (&d)[4], const unsigned short* buf,
                                       int kk, int lane, int wc) {
#pragma unroll
    for (int n = 0; n < 4; ++n) {
        const int r  = wc * 64 + n * 16 + (lane & 15);
        const int ch = (kk * 4 + (lane >> 4)) ^ (r & 7);
        d[n] = *(const bf16x8*)((const char*)buf + r * 128 + (ch << 4));
    }
}

__device__ __forceinline__ void mfma16(f32x4 (&acc)[8][4], int mh,
                                       const bf16x8 (&a)[4], const bf16x8 (&b)[4]) {
#pragma unroll
    for (int f = 0; f < 4; ++f)
#pragma unroll
        for (int n = 0; n < 4; ++n)
            acc[mh * 4 + f][n] = __builtin_amdgcn_mfma_f32_16x16x32_bf16(
                a[f], b[n], acc[mh * 4 + f][n], 0, 0, 0);
}

// One K-tile (BK=64), 4 phases, ONE barrier per phase (at phase end).
// Each phase: prefetch NEXT phase's fragments (reads issue pre-barrier;
// in-order lgkmcnt means MFMA(p)'s wait on reads(p-1) does NOT drain the
// newer reads(p) — they stay pending under the MFMA burst), issue stage
// DMAs, run MFMA(p), barrier. Wave skew is bounded to <1 phase by the
// end barrier.
// Race audit (1-barrier margins, skew<1 phase):
//  - A0/A1 (Acur): last read-issue = P2 (aY kh1); re-staged next tile P0/P1
//    -> >=2 barriers + P3 body + DMA flight before overwrite lands.  SAFE
//  - B0 (stB, restaged P2/P3 with B(u+2)): last read-issue = P1 (bY);
//    DMA issued post-P1-barrier, lands +>=200cy; ds_read retires ~120-300cy
//    after issue, one full barrier earlier.                           SAFE
//  - Bn=B1 (B(u+1), staged prev tile P2/P3): read at P3 (bX prefetch),
//    gated by vmcnt(2) at P2 end (FIFO: outstanding = prev P2/P3 B 4 +
//    cur P0/P1 A 4 + cur P2 B 2 = 10 -> drain to 2 completes prev-B and
//    cur-A; leaves cur P2's 2 newest).                                SAFE
//  - An (A(u+1), staged cur P0/P1): read at P3, also covered by vmcnt(2).
__device__ __forceinline__ void ktile_pipe(
    const unsigned short* Ac, const unsigned short* Bc,
    const unsigned short* An, const unsigned short* Bn,
    unsigned short* stA, unsigned short* stB,
    const unsigned short* gA1, const unsigned short* gB2,
    f32x4 (&acc)[8][4],
    bf16x8 (&aX)[4], bf16x8 (&aY)[4], bf16x8 (&bX)[4], bf16x8 (&bY)[4],
    size_t goff0, size_t goff1, int loff0, int loff1,
    int lane, int wr, int wc)
{
    // ---- P0: compute (mh0,kh0) = aX*bX; prefetch aY=(mh1,kh0) ----
    read_a(aY, Ac, 1, 0, lane, wr);
    ASYNC16(gA1 + goff0, stA + loff0);
    ASYNC16(gA1 + goff1, stA + loff1);
    SBAR0();
    __builtin_amdgcn_s_setprio(1);
    mfma16(acc, 0, aX, bX);
    __builtin_amdgcn_s_setprio(0);
    SBAR0();
    ENDP;
    // ---- P1: compute (mh1,kh0) = aY*bX; prefetch aX=(mh0,kh1), bY=(kh1) ----
    read_a(aX, Ac, 0, 1, lane, wr);
    read_b(bY, Bc, 1, lane, wc);
    ASYNC16(gA1 + 128 * D_IN + goff0, stA + 8192 + loff0);
    ASYNC16(gA1 + 128 * D_IN + goff1, stA + 8192 + loff1);
    SBAR0();
    __builtin_amdgcn_s_setprio(1);
    mfma16(acc, 1, aY, bX);
    __builtin_amdgcn_s_setprio(0);
    SBAR0();
    ENDP;
    // ---- P2: compute (mh0,kh1) = aX*bY; prefetch aY=(mh1,kh1) ----
    read_a(aY, Ac, 1, 1, lane, wr);
    ASYNC16(gB2 + goff0, stB + loff0);
    ASYNC16(gB2 + goff1, stB + loff1);
    SBAR0();
    __builtin_amdgcn_s_setprio(1);
    mfma16(acc, 0, aX, bY);
    __builtin_amdgcn_s_setprio(0);
    SBAR0();
    asm volatile("s_waitcnt vmcnt(2)");   // A(u+1)+B(u+1) landed -> P3 may read An/Bn
    ENDP;
    // ---- P3: compute (mh1,kh1) = aY*bY; prefetch NEXT tile aX, bX ----
    read_a(aX, An, 0, 0, lane, wr);
    read_b(bX, Bn, 0, lane, wc);
    ASYNC16(gB2 + 128 * D_IN + goff0, stB + 8192 + loff0);
    ASYNC16(gB2 + 128 * D_IN + goff1, stB + 8192 + loff1);
    SBAR0();
    __builtin_amdgcn_s_setprio(1);
    mfma16(acc, 1, aY, bY);
    __builtin_amdgcn_s_setprio(0);
    SBAR0();
    ENDP;
}

__global__ __launch_bounds__(512, 2)
void octo_gemm_8ph(const unsigned short* __restrict__ Xb,
                   const unsigned short* __restrict__ Wb,
                   float* __restrict__ Y, int M)
{
    // LDS: 2 K-tile double buffer; A(256x64) + B(256x64) bf16 each = 128 KiB.
    // Element (r,k): byte r*128 + ((chunk ^ (r&7))<<4) + low, chunk=(k*2)>>4;
    // linear LDS dest + inverse-swizzled GLOBAL source (rule #21).
    __shared__ __align__(16) unsigned short sm[65536];
    unsigned short* A0 = sm;
    unsigned short* A1 = sm + 16384;
    unsigned short* B0 = sm + 32768;
    unsigned short* B1 = sm + 49152;

    const int tid  = threadIdx.x;
    const int lane = tid & 63;
    const int wave = tid >> 6;
    const int wr   = wave >> 2;      // 2x4 wave grid; wave owns 128x64 output
    const int wc   = wave & 3;

    const int nbn = D_OUT / 256;                // 16
    const int nwg = (M / 256) * nbn;            // 512
    int bid = blockIdx.x;
    int cpx = nwg >> 3;                         // bijective XCD swizzle (nwg%8==0)
    int wg  = (bid & 7) * cpx + (bid >> 3);
    const int bm = wg / nbn, bn = wg % nbn;
    const int row0 = bm * 256, col0 = bn * 256;

    // staging geometry: half-tile = 128 rows x 64 cols bf16; 2 loads/thread
    const int srow  = tid >> 3;                 // 0..63
    const int sch   = tid & 7;                  // 16B chunk
    const size_t goff0 = (size_t)srow * D_IN + (size_t)((sch ^ (srow & 7)) * 8);
    const size_t goff1 = goff0 + (size_t)64 * D_IN;   // (64+srow)&7 == srow&7
    const int loff0 = tid * 8;                  // ushort elems; = lane*16B per wave
    const int loff1 = loff0 + 4096;

    const unsigned short* gX = Xb + (size_t)row0 * D_IN;
    const unsigned short* gW = Wb + (size_t)col0 * D_IN;

    f32x4 acc[8][4];
    #pragma unroll
    for (int m = 0; m < 8; ++m)
        #pragma unroll
        for (int n = 0; n < 4; ++n)
            acc[m][n] = (f32x4){0.f, 0.f, 0.f, 0.f};

    // ---- prologue: tile0 A+B -> buf0, tile1 B -> buf1.B (6 half-tiles) ----
    ASYNC16(gX + goff0, A0 + loff0);              ASYNC16(gX + goff1, A0 + loff1);
    ASYNC16(gX + 128 * D_IN + goff0, A0 + 8192 + loff0);
    ASYNC16(gX + 128 * D_IN + goff1, A0 + 8192 + loff1);
    ASYNC16(gW + goff0, B0 + loff0);              ASYNC16(gW + goff1, B0 + loff1);
    ASYNC16(gW + 128 * D_IN + goff0, B0 + 8192 + loff0);
    ASYNC16(gW + 128 * D_IN + goff1, B0 + 8192 + loff1);
    ASYNC16(gW + 64 + goff0, B1 + loff0);         ASYNC16(gW + 64 + goff1, B1 + loff1);
    ASYNC16(gW + 64 + 128 * D_IN + goff0, B1 + 8192 + loff0);
    ASYNC16(gW + 64 + 128 * D_IN + goff1, B1 + 8192 + loff1);
    asm volatile("s_waitcnt vmcnt(4)");           // tile0's 8 loads landed
    ENDP;

    // prime the register pipeline: tile0's (mh0,kh0) A-frags + b(kh0)
    bf16x8 aX[4], aY[4], bX[4], bY[4];
    read_a(aX, A0, 0, 0, lane, wr);
    read_b(bX, B0, 0, lane, wc);

    for (int i = 0; i < NT / 2; ++i) {
        const int u = 2 * i;
        // tail iterations stage wrapped tiles (&63): keeps vmcnt counts uniform;
        // wrapped data lands in regions never read again (race-free; last
        // tile's P3 cross-tile prefetch reads dead values that feed no MFMA).
        const unsigned short* gA1t = gX + ((u + 1) & (NT - 1)) * 64;
        const unsigned short* gA2t = gX + ((u + 2) & (NT - 1)) * 64;
        const unsigned short* gB2t = gW + ((u + 2) & (NT - 1)) * 64;
        const unsigned short* gB3t = gW + ((u + 3) & (NT - 1)) * 64;

        // tile u from buf0: stage A(u+1)->A1, B(u+2)->B0; P3 prefetch from A1/B1
        ktile_pipe(A0, B0, A1, B1, A1, B0, gA1t, gB2t,
                   acc, aX, aY, bX, bY,
                   goff0, goff1, loff0, loff1, lane, wr, wc);
        // tile u+1 from buf1: stage A(u+2)->A0, B(u+3)->B1; P3 prefetch from A0/B0
        ktile_pipe(A1, B1, A0, B0, A0, B1, gA2t, gB3t,
                   acc, aX, aY, bX, bY,
                   goff0, goff1, loff0, loff1, lane, wr, wc);
    }

    // epilogue: C/D layout col=lane&15, row=(lane>>4)*4+reg  [m89/m91]
    const int rl = (lane >> 4) << 2;
    const int cl = lane & 15;
    #pragma unroll
    for (int m = 0; m < 8; ++m) {
        const int rg = row0 + wr * 128 + m * 16 + rl;
        #pragma unroll
        for (int n = 0; n < 4; ++n) {
            const int cg = col0 + wc * 64 + n * 16 + cl;
            #pragma unroll
            for (int q = 0; q < 4; ++q)
                Y[(size_t)(rg + q) * D_OUT + cg] = acc[m][n][q];
        }
    }
}

// ---------- fallback: fused fp32-staging kernel (no workspace) ----------

#define BM 128
#define BN 128
#define BK 64

__global__ __launch_bounds__(256)
void octo_gemm_f32(const float* __restrict__ X, const float* __restrict__ W,
                   float* __restrict__ Y, int M)
{
    __shared__ __align__(16) unsigned short As[BM * BK];
    __shared__ __align__(16) unsigned short Bs[BN * BK];

    const int tid  = threadIdx.x;
    const int lane = tid & 63;
    const int wave = tid >> 6;
    const int wr   = wave >> 1;
    const int wc   = wave & 1;

    const int nbn = D_OUT / BN;
    const int nwg = (M / BM) * nbn;
    int bid = blockIdx.x;
    int wg  = bid;
    if ((nwg & 7) == 0) {
        int cpx = nwg >> 3;
        wg = (bid & 7) * cpx + (bid >> 3);
    }
    const int bm = wg / nbn, bn = wg % nbn;
    const int row0  = bm * BM;
    const int col0  = bn * BN;
    const int icomp = col0 >> 9;
    const int noff  = col0 & (NC - 1);

    const int srow = tid >> 4;
    const int scol = (tid & 15) << 2;

    f32x4 acc[4][4];
    #pragma unroll
    for (int m = 0; m < 4; ++m)
        #pragma unroll
        for (int n = 0; n < 4; ++n)
            acc[m][n] = (f32x4){0.f, 0.f, 0.f, 0.f};

    char* AsB = (char*)As;
    char* BsB = (char*)Bs;
    const int byteC = scol << 1;

    for (int step = 0; step < NT; ++step) {
        const int k0 = step * BK;
        const int j  = k0 >> 9;
        const int kc = k0 & (KC - 1);
        const float sgn = c_sign[icomp * 8 + j];
        const int   w   = icomp ^ j;
        const float* Wp = W + (((size_t)w * NC + noff) * KC + kc);
        const float* Xp = X + ((size_t)row0 * D_IN + k0);

        __syncthreads();
        #pragma unroll
        for (int p = 0; p < 8; ++p) {
            const int r  = p * 16 + srow;
            const int sb = r * 128 + ((((byteC >> 4) ^ (r & 7)) << 4)) + (byteC & 8);
            const float4 va = *(const float4*)(&Xp[(size_t)r * D_IN + scol]);
            *(uint2*)(AsB + sb) = make_uint2(pack2bf16(va.x, va.y),
                                             pack2bf16(va.z, va.w));
            const float4 vb = *(const float4*)(&Wp[(size_t)r * KC + scol]);
            *(uint2*)(BsB + sb) = make_uint2(pack2bf16(vb.x * sgn, vb.y * sgn),
                                             pack2bf16(vb.z * sgn, vb.w * sgn));
        }
        __syncthreads();

        #pragma unroll
        for (int kk = 0; kk < 2; ++kk) {
            bf16x8 af[4], bf[4];
            #pragma unroll
            for (int m = 0; m < 4; ++m) {
                const int r = wr * 64 + m * 16 + (lane & 15);
                const int chunk = (kk * 4 + (lane >> 4)) ^ (r & 7);
                af[m] = *(const bf16x8*)(AsB + r * 128 + (chunk << 4));
            }
            #pragma unroll
            for (int n = 0; n < 4; ++n) {
                const int r = wc * 64 + n * 16 + (lane & 15);
                const int chunk = (kk * 4 + (lane >> 4)) ^ (r & 7);
                bf[n] = *(const bf16x8*)(BsB + r * 128 + (chunk << 4));
            }
            #pragma unroll
            for (int m = 0; m < 4; ++m)
                #pragma unroll
                for (int n = 0; n < 4; ++n)
                    acc[m][n] = __builtin_amdgcn_mfma_f32_16x16x32_bf16(
                        af[m], bf[n], acc[m][n], 0, 0, 0);
        }
    }

    const int rl = (lane >> 4) << 2;
    const int cl = lane & 15;
    #pragma unroll
    for (int m = 0; m < 4; ++m) {
        const int rg = row0 + wr * 64 + m * 16 + rl;
        #pragma unroll
        for (int n = 0; n < 4; ++n) {
            const int cg = col0 + wc * 64 + n * 16 + cl;
            #pragma unroll
            for (int q = 0; q < 4; ++q)
                Y[(size_t)(rg + q) * D_OUT + cg] = acc[m][n][q];
        }
    }
}

extern "C" void kernel_launch(void* const* d_in, const int* in_sizes, int n_in,
                              void* d_out, int out_size, void* d_ws, size_t ws_size,
                              hipStream_t stream) {
    const float* X = (const float*)d_in[0];   // [B*T, 4096] fp32
    const float* W = (const float*)d_in[1];   // [8, 512, 512] fp32
    float* Y = (float*)d_out;                 // [B*T, 4096] fp32
    const int M = in_sizes[0] / D_IN;         // 8192

    const size_t xb_bytes = (size_t)M * D_IN * sizeof(unsigned short);      // 64 MB
    const size_t wb_bytes = (size_t)D_OUT * D_IN * sizeof(unsigned short);  // 32 MB

    if (ws_size >= xb_bytes + wb_bytes && (M % 256) == 0) {
        unsigned short* Xb = (unsigned short*)d_ws;
        unsigned short* Wb = (unsigned short*)((char*)d_ws + xb_bytes);
        const int n8x = M * D_IN / 8;
        hipLaunchKernelGGL(conv_x, dim3(n8x / 256), dim3(256), 0, stream, X, Xb, n8x);
        hipLaunchKernelGGL(conv_w, dim3((D_OUT * D_IN / 8) / 256), dim3(256), 0, stream, W, Wb);
        const int nwg = (M / 256) * (D_OUT / 256);   // 512
        hipLaunchKernelGGL(octo_gemm_8ph, dim3(nwg), dim3(512), 0, stream, Xb, Wb, Y, M);
    } else {
        const int nwg = (M / BM) * (D_OUT / BN);
        hipLaunchKernelGGL(octo_gemm_f32, dim3(nwg), dim3(256), 0, stream, X, W, Y, M);
    }
}

// Round 10
// 255.091 us; speedup vs baseline: 1.4884x; 1.0100x over previous
//
#include <hip/hip_runtime.h>
#include <stdint.h>

typedef __attribute__((ext_vector_type(8))) short bf16x8;
typedef __attribute__((ext_vector_type(4))) float f32x4;

#define D_IN  4096
#define D_OUT 4096
#define KC 512   // per-component input dim
#define NC 512   // per-component output dim
#define NT 64    // K-tiles of BK=64

// SIGN_TABLE[i][j], row-major
__constant__ float c_sign[64] = {
 +1,-1,-1,-1,-1,-1,-1,-1,
 +1,+1,+1,-1,+1,-1,-1,+1,
 +1,-1,+1,+1,+1,+1,-1,-1,
 +1,+1,-1,+1,+1,-1,+1,-1,
 +1,-1,-1,-1,+1,+1,+1,+1,
 +1,+1,-1,+1,-1,+1,-1,+1,
 +1,+1,+1,-1,-1,+1,+1,-1,
 +1,-1,+1,+1,-1,-1,+1,+1,
};

__device__ inline unsigned int pack2bf16(float a, float b) {
    unsigned int ua = __builtin_bit_cast(unsigned int, a);
    unsigned int ub = __builtin_bit_cast(unsigned int, b);
    ua = (ua + 0x7FFFu + ((ua >> 16) & 1u)) >> 16;
    ub = (ub + 0x7FFFu + ((ub >> 16) & 1u)) >> 16;
    return ua | (ub << 16);
}

typedef __attribute__((address_space(1))) const unsigned int gas_u32;
typedef __attribute__((address_space(3))) unsigned int las_u32;
#define ASYNC16(g, l) __builtin_amdgcn_global_load_lds((gas_u32*)(g), (las_u32*)(l), 16, 0, 0)
#define ENDP do { __builtin_amdgcn_s_barrier(); asm volatile("" ::: "memory"); } while (0)

// ---------- pre-conversion kernels ----------

__global__ __launch_bounds__(256)
void conv_x(const float* __restrict__ in, unsigned short* __restrict__ out, int n8) {
    int i = blockIdx.x * blockDim.x + threadIdx.x;
    if (i >= n8) return;
    const float4 a = ((const float4*)in)[(size_t)i * 2];
    const float4 b = ((const float4*)in)[(size_t)i * 2 + 1];
    uint4 o;
    o.x = pack2bf16(a.x, a.y); o.y = pack2bf16(a.z, a.w);
    o.z = pack2bf16(b.x, b.y); o.w = pack2bf16(b.z, b.w);
    ((uint4*)out)[i] = o;
}

// Wbig[i*512+n][j*512+k] = sign[i][j] * W[i^j][n][k], fp32 -> bf16
__global__ __launch_bounds__(256)
void conv_w(const float* __restrict__ W, unsigned short* __restrict__ out) {
    int gid = blockIdx.x * blockDim.x + threadIdx.x;   // 0 .. 4096*512-1
    int row = gid >> 9;
    int c8  = gid & 511;
    int i = row >> 9, n = row & 511;
    int j = c8 >> 6;
    int k = (c8 & 63) << 3;
    float sgn = c_sign[i * 8 + j];
    const float* src = W + ((((i ^ j) * NC + n) * KC) + k);
    float4 a = *(const float4*)(src);
    float4 b = *(const float4*)(src + 4);
    uint4 o;
    o.x = pack2bf16(a.x * sgn, a.y * sgn); o.y = pack2bf16(a.z * sgn, a.w * sgn);
    o.z = pack2bf16(b.x * sgn, b.y * sgn); o.w = pack2bf16(b.z * sgn, b.w * sgn);
    ((uint4*)out)[gid] = o;
}

// ---------- 256x256 bf16 GEMM, one-ahead pipeline, 3 windows/tile ----------

__device__ __forceinline__ void read_a(bf16x8 (&d)[4], const unsigned short* buf,
                                       int mh, int kk, int lane, int wr) {
#pragma unroll
    for (int f = 0; f < 4; ++f) {
        const int r  = wr * 128 + (mh * 4 + f) * 16 + (lane & 15);
        const int ch = (kk * 4 + (lane >> 4)) ^ (r & 7);
        d[f] = *(const bf16x8*)((const char*)buf + r * 128 + (ch << 4));
    }
}

__device__ __forceinline__ void read_b(bf16x8 (&d)[4], const unsigned short* buf,
                                       int kk, int lane, int wc) {
#pragma unroll
    for (int n = 0; n < 4; ++n) {
        const int r  = wc * 64 + n * 16 + (lane & 15);
        const int ch = (kk * 4 + (lane >> 4)) ^ (r & 7);
        d[n] = *(const bf16x8*)((const char*)buf + r * 128 + (ch << 4));
    }
}

__device__ __forceinline__ void mfma16(f32x4 (&acc)[8][4], int mh,
                                       const bf16x8 (&a)[4], const bf16x8 (&b)[4]) {
#pragma unroll
    for (int f = 0; f < 4; ++f)
#pragma unroll
        for (int n = 0; n < 4; ++n)
            acc[mh * 4 + f][n] = __builtin_amdgcn_mfma_f32_16x16x32_bf16(
                a[f], b[n], acc[mh * 4 + f][n], 0, 0, 0);
}

// One K-tile (BK=64) as 3 windows (was 4 phases):
//   W0 = {(mh0,kh0) + (mh1,kh0) bursts},  W1 = {(mh0,kh1)},  W2 = {(mh1,kh1)}.
// One-ahead register pipeline: each window reads the NEXT burst's fragments;
// no sched_barrier pins — compiler interleaves ds_read issue into the MFMA
// bursts (SSA renaming keeps old-aX alive for W0 burst1 while new aX loads).
// Race audit (skew < 1 window, barriers at window ends):
//  - stB (=Bc): bY read-issue in W0; B(u+2)h1 DMA issued in W1, separated by
//    the W0-end barrier.                                               SAFE
//  - stA (=An): prior content A(u-1) last read-issue = tile u-1 W1 (aY kh1);
//    >=2 barriers before tile u W0's DMAs.                             SAFE
//  - W2 reads An=A(u+1), Bn=B(u+1): vmcnt(2) at W1-end (FIFO: outstanding =
//    prev W1/W2 B(u+1) 4 + cur W0 A(u+1) 4 + cur W1 B(u+2)h1 2 = 10; drain
//    to 2 completes B(u+1)+A(u+1)) + W1-end barrier (all waves drained).SAFE
//  - vmcnt asm is immediately followed by ENDP's "memory" clobber, so the
//    W2 ds_reads cannot be hoisted above the wait.
__device__ __forceinline__ void ktile_pipe(
    const unsigned short* Ac, const unsigned short* Bc,
    const unsigned short* An, const unsigned short* Bn,
    unsigned short* stA, unsigned short* stB,
    const unsigned short* gA1, const unsigned short* gB2,
    f32x4 (&acc)[8][4],
    bf16x8 (&aX)[4], bf16x8 (&aY)[4], bf16x8 (&bX)[4], bf16x8 (&bY)[4],
    size_t goff0, size_t goff1, int loff0, int loff1,
    int lane, int wr, int wc)
{
    // ---- W0: (mh0,kh0) = aX*bX, then (mh1,kh0) = aY*bX ----
    read_a(aY, Ac, 1, 0, lane, wr);
    __builtin_amdgcn_s_setprio(1);
    mfma16(acc, 0, aX, bX);
    __builtin_amdgcn_s_setprio(0);
    read_a(aX, Ac, 0, 1, lane, wr);        // for W1 (old aX consumed above)
    read_b(bY, Bc, 1, lane, wc);           // for W1/W2
    ASYNC16(gA1 + goff0, stA + loff0);
    ASYNC16(gA1 + goff1, stA + loff1);
    ASYNC16(gA1 + 128 * D_IN + goff0, stA + 8192 + loff0);
    ASYNC16(gA1 + 128 * D_IN + goff1, stA + 8192 + loff1);
    __builtin_amdgcn_s_setprio(1);
    mfma16(acc, 1, aY, bX);
    __builtin_amdgcn_s_setprio(0);
    ENDP;
    // ---- W1: (mh0,kh1) = aX*bY ----
    read_a(aY, Ac, 1, 1, lane, wr);        // for W2
    ASYNC16(gB2 + goff0, stB + loff0);
    ASYNC16(gB2 + goff1, stB + loff1);
    __builtin_amdgcn_s_setprio(1);
    mfma16(acc, 0, aX, bY);
    __builtin_amdgcn_s_setprio(0);
    asm volatile("s_waitcnt vmcnt(2)");    // A(u+1)+B(u+1) landed (see audit)
    ENDP;
    // ---- W2: (mh1,kh1) = aY*bY; prefetch next tile's aX, bX ----
    read_a(aX, An, 0, 0, lane, wr);
    read_b(bX, Bn, 0, lane, wc);
    ASYNC16(gB2 + 128 * D_IN + goff0, stB + 8192 + loff0);
    ASYNC16(gB2 + 128 * D_IN + goff1, stB + 8192 + loff1);
    __builtin_amdgcn_s_setprio(1);
    mfma16(acc, 1, aY, bY);
    __builtin_amdgcn_s_setprio(0);
    ENDP;
}

__global__ __launch_bounds__(512, 2)
void octo_gemm_8ph(const unsigned short* __restrict__ Xb,
                   const unsigned short* __restrict__ Wb,
                   float* __restrict__ Y, int M)
{
    // LDS: 2 K-tile double buffer; A(256x64) + B(256x64) bf16 each = 128 KiB.
    // Element (r,k): byte r*128 + ((chunk ^ (r&7))<<4) + low, chunk=(k*2)>>4;
    // linear LDS dest + inverse-swizzled GLOBAL source (rule #21).
    __shared__ __align__(16) unsigned short sm[65536];
    unsigned short* A0 = sm;
    unsigned short* A1 = sm + 16384;
    unsigned short* B0 = sm + 32768;
    unsigned short* B1 = sm + 49152;

    const int tid  = threadIdx.x;
    const int lane = tid & 63;
    const int wave = tid >> 6;
    const int wr   = wave >> 2;      // 2x4 wave grid; wave owns 128x64 output
    const int wc   = wave & 3;

    const int nbn = D_OUT / 256;                // 16
    const int nwg = (M / 256) * nbn;            // 512
    int bid = blockIdx.x;
    int cpx = nwg >> 3;                         // bijective XCD swizzle (nwg%8==0)
    int wg  = (bid & 7) * cpx + (bid >> 3);
    const int bm = wg / nbn, bn = wg % nbn;
    const int row0 = bm * 256, col0 = bn * 256;

    // staging geometry: half-tile = 128 rows x 64 cols bf16; 2 loads/thread
    const int srow  = tid >> 3;                 // 0..63
    const int sch   = tid & 7;                  // 16B chunk
    const size_t goff0 = (size_t)srow * D_IN + (size_t)((sch ^ (srow & 7)) * 8);
    const size_t goff1 = goff0 + (size_t)64 * D_IN;   // (64+srow)&7 == srow&7
    const int loff0 = tid * 8;                  // ushort elems; = lane*16B per wave
    const int loff1 = loff0 + 4096;

    const unsigned short* gX = Xb + (size_t)row0 * D_IN;
    const unsigned short* gW = Wb + (size_t)col0 * D_IN;

    f32x4 acc[8][4];
    #pragma unroll
    for (int m = 0; m < 8; ++m)
        #pragma unroll
        for (int n = 0; n < 4; ++n)
            acc[m][n] = (f32x4){0.f, 0.f, 0.f, 0.f};

    // ---- prologue: tile0 A+B -> buf0, tile1 B -> buf1.B (6 half-tiles) ----
    ASYNC16(gX + goff0, A0 + loff0);              ASYNC16(gX + goff1, A0 + loff1);
    ASYNC16(gX + 128 * D_IN + goff0, A0 + 8192 + loff0);
    ASYNC16(gX + 128 * D_IN + goff1, A0 + 8192 + loff1);
    ASYNC16(gW + goff0, B0 + loff0);              ASYNC16(gW + goff1, B0 + loff1);
    ASYNC16(gW + 128 * D_IN + goff0, B0 + 8192 + loff0);
    ASYNC16(gW + 128 * D_IN + goff1, B0 + 8192 + loff1);
    ASYNC16(gW + 64 + goff0, B1 + loff0);         ASYNC16(gW + 64 + goff1, B1 + loff1);
    ASYNC16(gW + 64 + 128 * D_IN + goff0, B1 + 8192 + loff0);
    ASYNC16(gW + 64 + 128 * D_IN + goff1, B1 + 8192 + loff1);
    asm volatile("s_waitcnt vmcnt(4)");           // tile0's 8 loads landed
    ENDP;

    // prime the register pipeline: tile0's (mh0,kh0) A-frags + b(kh0)
    bf16x8 aX[4], aY[4], bX[4], bY[4];
    read_a(aX, A0, 0, 0, lane, wr);
    read_b(bX, B0, 0, lane, wc);

    for (int i = 0; i < NT / 2; ++i) {
        const int u = 2 * i;
        // tail iterations stage wrapped tiles (&63): keeps vmcnt counts uniform;
        // wrapped data lands in regions never read again (race-free; last
        // tile's W2 cross-tile prefetch reads dead values that feed no MFMA).
        const unsigned short* gA1t = gX + ((u + 1) & (NT - 1)) * 64;
        const unsigned short* gA2t = gX + ((u + 2) & (NT - 1)) * 64;
        const unsigned short* gB2t = gW + ((u + 2) & (NT - 1)) * 64;
        const unsigned short* gB3t = gW + ((u + 3) & (NT - 1)) * 64;

        // tile u from buf0: stage A(u+1)->A1, B(u+2)->B0; W2 prefetch from A1/B1
        ktile_pipe(A0, B0, A1, B1, A1, B0, gA1t, gB2t,
                   acc, aX, aY, bX, bY,
                   goff0, goff1, loff0, loff1, lane, wr, wc);
        // tile u+1 from buf1: stage A(u+2)->A0, B(u+3)->B1; W2 prefetch from A0/B0
        ktile_pipe(A1, B1, A0, B0, A0, B1, gA2t, gB3t,
                   acc, aX, aY, bX, bY,
                   goff0, goff1, loff0, loff1, lane, wr, wc);
    }

    // epilogue: C/D layout col=lane&15, row=(lane>>4)*4+reg  [m89/m91]
    const int rl = (lane >> 4) << 2;
    const int cl = lane & 15;
    #pragma unroll
    for (int m = 0; m < 8; ++m) {
        const int rg = row0 + wr * 128 + m * 16 + rl;
        #pragma unroll
        for (int n = 0; n < 4; ++n) {
            const int cg = col0 + wc * 64 + n * 16 + cl;
            #pragma unroll
            for (int q = 0; q < 4; ++q)
                Y[(size_t)(rg + q) * D_OUT + cg] = acc[m][n][q];
        }
    }
}

// ---------- fallback: fused fp32-staging kernel (no workspace) ----------

#define BM 128
#define BN 128
#define BK 64

__global__ __launch_bounds__(256)
void octo_gemm_f32(const float* __restrict__ X, const float* __restrict__ W,
                   float* __restrict__ Y, int M)
{
    __shared__ __align__(16) unsigned short As[BM * BK];
    __shared__ __align__(16) unsigned short Bs[BN * BK];

    const int tid  = threadIdx.x;
    const int lane = tid & 63;
    const int wave = tid >> 6;
    const int wr   = wave >> 1;
    const int wc   = wave & 1;

    const int nbn = D_OUT / BN;
    const int nwg = (M / BM) * nbn;
    int bid = blockIdx.x;
    int wg  = bid;
    if ((nwg & 7) == 0) {
        int cpx = nwg >> 3;
        wg = (bid & 7) * cpx + (bid >> 3);
    }
    const int bm = wg / nbn, bn = wg % nbn;
    const int row0  = bm * BM;
    const int col0  = bn * BN;
    const int icomp = col0 >> 9;
    const int noff  = col0 & (NC - 1);

    const int srow = tid >> 4;
    const int scol = (tid & 15) << 2;

    f32x4 acc[4][4];
    #pragma unroll
    for (int m = 0; m < 4; ++m)
        #pragma unroll
        for (int n = 0; n < 4; ++n)
            acc[m][n] = (f32x4){0.f, 0.f, 0.f, 0.f};

    char* AsB = (char*)As;
    char* BsB = (char*)Bs;
    const int byteC = scol << 1;

    for (int step = 0; step < NT; ++step) {
        const int k0 = step * BK;
        const int j  = k0 >> 9;
        const int kc = k0 & (KC - 1);
        const float sgn = c_sign[icomp * 8 + j];
        const int   w   = icomp ^ j;
        const float* Wp = W + (((size_t)w * NC + noff) * KC + kc);
        const float* Xp = X + ((size_t)row0 * D_IN + k0);

        __syncthreads();
        #pragma unroll
        for (int p = 0; p < 8; ++p) {
            const int r  = p * 16 + srow;
            const int sb = r * 128 + ((((byteC >> 4) ^ (r & 7)) << 4)) + (byteC & 8);
            const float4 va = *(const float4*)(&Xp[(size_t)r * D_IN + scol]);
            *(uint2*)(AsB + sb) = make_uint2(pack2bf16(va.x, va.y),
                                             pack2bf16(va.z, va.w));
            const float4 vb = *(const float4*)(&Wp[(size_t)r * KC + scol]);
            *(uint2*)(BsB + sb) = make_uint2(pack2bf16(vb.x * sgn, vb.y * sgn),
                                             pack2bf16(vb.z * sgn, vb.w * sgn));
        }
        __syncthreads();

        #pragma unroll
        for (int kk = 0; kk < 2; ++kk) {
            bf16x8 af[4], bf[4];
            #pragma unroll
            for (int m = 0; m < 4; ++m) {
                const int r = wr * 64 + m * 16 + (lane & 15);
                const int chunk = (kk * 4 + (lane >> 4)) ^ (r & 7);
                af[m] = *(const bf16x8*)(AsB + r * 128 + (chunk << 4));
            }
            #pragma unroll
            for (int n = 0; n < 4; ++n) {
                const int r = wc * 64 + n * 16 + (lane & 15);
                const int chunk = (kk * 4 + (lane >> 4)) ^ (r & 7);
                bf[n] = *(const bf16x8*)(BsB + r * 128 + (chunk << 4));
            }
            #pragma unroll
            for (int m = 0; m < 4; ++m)
                #pragma unroll
                for (int n = 0; n < 4; ++n)
                    acc[m][n] = __builtin_amdgcn_mfma_f32_16x16x32_bf16(
                        af[m], bf[n], acc[m][n], 0, 0, 0);
        }
    }

    const int rl = (lane >> 4) << 2;
    const int cl = lane & 15;
    #pragma unroll
    for (int m = 0; m < 4; ++m) {
        const int rg = row0 + wr * 64 + m * 16 + rl;
        #pragma unroll
        for (int n = 0; n < 4; ++n) {
            const int cg = col0 + wc * 64 + n * 16 + cl;
            #pragma unroll
            for (int q = 0; q < 4; ++q)
                Y[(size_t)(rg + q) * D_OUT + cg] = acc[m][n][q];
        }
    }
}

extern "C" void kernel_launch(void* const* d_in, const int* in_sizes, int n_in,
                              void* d_out, int out_size, void* d_ws, size_t ws_size,
                              hipStream_t stream) {
    const float* X = (const float*)d_in[0];   // [B*T, 4096] fp32
    const float* W = (const float*)d_in[1];   // [8, 512, 512] fp32
    float* Y = (float*)d_out;                 // [B*T, 4096] fp32
    const int M = in_sizes[0] / D_IN;         // 8192

    const size_t xb_bytes = (size_t)M * D_IN * sizeof(unsigned short);      // 64 MB
    const size_t wb_bytes = (size_t)D_OUT * D_IN * sizeof(unsigned short);  // 32 MB

    if (ws_size >= xb_bytes + wb_bytes && (M % 256) == 0) {
        unsigned short* Xb = (unsigned short*)d_ws;
        unsigned short* Wb = (unsigned short*)((char*)d_ws + xb_bytes);
        const int n8x = M * D_IN / 8;
        hipLaunchKernelGGL(conv_x, dim3(n8x / 256), dim3(256), 0, stream, X, Xb, n8x);
        hipLaunchKernelGGL(conv_w, dim3((D_OUT * D_IN / 8) / 256), dim3(256), 0, stream, W, Wb);
        const int nwg = (M / 256) * (D_OUT / 256);   // 512
        hipLaunchKernelGGL(octo_gemm_8ph, dim3(nwg), dim3(512), 0, stream, Xb, Wb, Y, M);
    } else {
        const int nwg = (M / BM) * (D_OUT / BN);
        hipLaunchKernelGGL(octo_gemm_f32, dim3(nwg), dim3(256), 0, stream, X, W, Y, M);
    }
}